// Round 4
// baseline (732.010 us; speedup 1.0000x reference)
//
#include <hip/hip_runtime.h>
#include <stdint.h>

typedef __bf16 bf16_t;
typedef __bf16 bf16x8 __attribute__((ext_vector_type(8)));
typedef __bf16 bf16x4 __attribute__((ext_vector_type(4)));
typedef float f32x4 __attribute__((ext_vector_type(4)));
typedef unsigned int u32;

#define DEVINL static __device__ __forceinline__

constexpr int BB = 4;
constexpr int SEQ = 2048;
constexpr int HID = 1024;
constexpr int NL = 4;
constexpr int MR = BB * SEQ;  // 8192
constexpr float LN_EPS = 1e-5f;
constexpr float MASK_NEG = -1e9f;

DEVINL f32x4 mfma16x16x32(bf16x8 a, bf16x8 b, f32x4 c) {
  return __builtin_amdgcn_mfma_f32_16x16x32_bf16(a, b, c, 0, 0, 0);
}

// async global->LDS, 16B/lane; LDS dest wave-uniform base + lane*16.
DEVINL void gload_lds16(const bf16_t* g, bf16_t* l) {
  __builtin_amdgcn_global_load_lds(
      (const __attribute__((address_space(1))) u32*)g,
      (__attribute__((address_space(3))) u32*)l, 16, 0, 0);
}

// ---------------------------------------------------------------------------
// 256x256 8-phase NT GEMM. BK=64, 512 threads (8 waves 2Mx4N), per-wave C =
// 128x64. LDS: A[2 parity][256][64] + B same = 128 KiB, XOR slot-swizzle.
//
// Staging (consumption-ordered, 2-K-tile prefetch): region R of K-tile X is
// written into parity X&1 in the phase AFTER the current occupant (X-2)'s
// reads of R completed (barrier-separated => race-free). Per K-tile kt:
//   p0: A(kt+1) h1,h3   (rows 64-128,192-256 of parity kt+1: occupant kt-1
//                        read them at its p2/p3 -> free)
//   p1: B(kt+2) h0,h1   (B parity kt fully read at kt's p0 -> free)
//   p2: A(kt+2) h0,h2   (rows 0-64,128-192 of parity kt read at p0/p1)
//   p3: B(kt+2) h2,h3
// One counted gate per K-tile: vmcnt(6) after p3's MFMA = drain everything
// older than the last 3 phases = exactly the loads kt+1 reads. Ages 5-7
// phases >> HBM latency. Tail: vmcnt(0) for kt >= NT-3.
// EPI 0: QKV  z in {0,1,2} -> (W,bias,out); bf16 = acc + bias
// EPI 1: QK^T z = batch;    bf16 = acc * 1/sqrt(H)
// EPI 2: PV split-K2: z = batch*2+khalf; bf16 partial
// ---------------------------------------------------------------------------
template <int EPI>
__global__ __launch_bounds__(512, 2) void gemm8(
    const bf16_t* __restrict__ Ab, const bf16_t* __restrict__ B0,
    const bf16_t* __restrict__ B1, const bf16_t* __restrict__ B2,
    const float* __restrict__ bias0, const float* __restrict__ bias1,
    const float* __restrict__ bias2, bf16_t* __restrict__ o0,
    bf16_t* __restrict__ o1, bf16_t* __restrict__ o2) {
  constexpr int TM = (EPI == 0) ? 32 : 8;
  constexpr int TN = (EPI == 1) ? 8 : 4;
  constexpr int LDA = (EPI == 2) ? SEQ : HID;
  constexpr int LDB = (EPI == 2) ? SEQ : HID;
  constexpr int LDC = (EPI == 1) ? SEQ : HID;
  constexpr int NT = 16;  // K-tiles of 64 (K extent 1024 everywhere)

  __shared__ bf16_t lA[2 * 16384];
  __shared__ bf16_t lB[2 * 16384];

  // bijective XCD swizzle (grid % 8 == 0 for all launches)
  const int nwg = gridDim.x;
  int Lb = blockIdx.x;
  Lb = (Lb & 7) * (nwg >> 3) + (Lb >> 3);
  const int z = Lb / (TM * TN);
  const int rem = Lb - z * (TM * TN);
  const int tm = rem / TN;
  const int tn = rem - tm * TN;
  const int brow = tm * 256, bcol = tn * 256;

  const bf16_t* A;
  const bf16_t* B;
  const float* bias = nullptr;
  bf16_t* outb = nullptr;
  if (EPI == 0) {
    A = Ab;
    B = (z == 0) ? B0 : (z == 1) ? B1 : B2;
    bias = (z == 0) ? bias0 : (z == 1) ? bias1 : bias2;
    outb = (z == 0) ? o0 : (z == 1) ? o1 : o2;
  } else if (EPI == 1) {
    A = Ab + (size_t)z * SEQ * HID;
    B = B0 + (size_t)z * SEQ * HID;
    outb = o0 + (size_t)z * SEQ * SEQ;
  } else {
    const int zb = z >> 1, kh = z & 1;
    A = Ab + (size_t)zb * SEQ * SEQ + kh * 1024;   // scores K-half
    B = B0 + (size_t)zb * HID * SEQ + kh * 1024;   // vT K-half
    outb = ((kh == 0) ? o0 : o1) + (size_t)zb * SEQ * HID;
  }

  const int t = threadIdx.x, wave = t >> 6, lane = t & 63;
  const int wm = wave >> 2, wn = wave & 3;
  const int fr = lane & 15, kb = lane >> 4;
  const int srow = t >> 3;                 // 0..63 (64 rows per gload call)
  const int cbk = (t & 7) ^ (srow & 7);    // pre-swizzled source slot
  const bf16_t* pAs = A + (size_t)(brow + srow) * LDA + cbk * 8;
  const bf16_t* pBs = B + (size_t)(bcol + srow) * LDB + cbk * 8;
  bf16_t* lAw = lA + wave * 512;
  bf16_t* lBw = lB + wave * 512;

  // stage 64-row chunk h (0..3) of K-tile X into parity X&1
#define SA(X_, h_)                                                       \
  gload_lds16(pAs + (size_t)((h_)*64) * LDA + (X_)*64,                   \
              lAw + ((X_)&1) * 16384 + (h_)*4096)
#define SB(X_, h_)                                                       \
  gload_lds16(pBs + (size_t)((h_)*64) * LDB + (X_)*64,                   \
              lBw + ((X_)&1) * 16384 + (h_)*4096)

  const char* lAc = (const char*)lA;
  const char* lBc = (const char*)lB;
  const int cX0 = ((kb ^ (fr & 7)) << 4);  // swizzled ds_read col (ks=0)
  const int cX1 = cX0 ^ 64;                // ks=1
  const int bRowOff = (wn & 1) * 64;

  f32x4 acc[8][4] = {};

  // prologue: full A(0),B(0); backlog that kt=-1,-2 would have staged:
  // A(1) h0,h2 and B(1) h0..h3. (A(1) h1,h3 issue at kt=0 p0.)
  SA(0, 0); SA(0, 1); SA(0, 2); SA(0, 3);
  SB(0, 0); SB(0, 1); SB(0, 2); SB(0, 3);
  SA(1, 0); SA(1, 2);
  SB(1, 0); SB(1, 1); SB(1, 2); SB(1, 3);
  asm volatile("s_waitcnt vmcnt(6)" ::: "memory");  // A(0),B(0) landed
  __builtin_amdgcn_s_barrier();

  for (int kt = 0; kt < NT; ++kt) {
    const char* aB = lAc + (size_t)(kt & 1) * 32768 + wm * 16384;
    const char* bB = lBc + (size_t)(kt & 1) * 32768 + (wn >> 1) * 16384;
    bf16x8 bf_[4][2];
#pragma unroll
    for (int p = 0; p < 4; ++p) {
      if (p == 0) {  // B-frags for the whole K-tile, kept in regs
#pragma unroll
        for (int n = 0; n < 4; ++n) {
          const int rb = (bRowOff + n * 16 + fr) * 128;
          bf_[n][0] = *(const bf16x8*)(bB + rb + cX0);
          bf_[n][1] = *(const bf16x8*)(bB + rb + cX1);
        }
      }
      const int ra0 = (p * 32 + fr) * 128;
      const int ra1 = (p * 32 + 16 + fr) * 128;
      bf16x8 a00 = *(const bf16x8*)(aB + ra0 + cX0);
      bf16x8 a01 = *(const bf16x8*)(aB + ra0 + cX1);
      bf16x8 a10 = *(const bf16x8*)(aB + ra1 + cX0);
      bf16x8 a11 = *(const bf16x8*)(aB + ra1 + cX1);
      // consumption-ordered staging (see header comment)
      if (p == 0 && kt + 1 < NT) { SA(kt + 1, 1); SA(kt + 1, 3); }
      if (p == 1 && kt + 2 < NT) { SB(kt + 2, 0); SB(kt + 2, 1); }
      if (p == 2 && kt + 2 < NT) { SA(kt + 2, 0); SA(kt + 2, 2); }
      if (p == 3 && kt + 2 < NT) { SB(kt + 2, 2); SB(kt + 2, 3); }
      __builtin_amdgcn_s_barrier();
      __builtin_amdgcn_s_setprio(1);
#pragma unroll
      for (int n = 0; n < 4; ++n) {
        acc[2 * p][n] = mfma16x16x32(a00, bf_[n][0], acc[2 * p][n]);
        acc[2 * p][n] = mfma16x16x32(a01, bf_[n][1], acc[2 * p][n]);
        acc[2 * p + 1][n] = mfma16x16x32(a10, bf_[n][0], acc[2 * p + 1][n]);
        acc[2 * p + 1][n] = mfma16x16x32(a11, bf_[n][1], acc[2 * p + 1][n]);
      }
      __builtin_amdgcn_s_setprio(0);
      if (p == 3) {  // once per K-tile; counted (never 0 until tail)
        if (kt < NT - 3)
          asm volatile("s_waitcnt vmcnt(6)" ::: "memory");
        else
          asm volatile("s_waitcnt vmcnt(0)" ::: "memory");
      }
      __builtin_amdgcn_s_barrier();
    }
  }

  // C/D layout (m89): col = lane&15, row = (lane>>4)*4 + j
  const int qr = lane >> 4;
  const int crow = brow + wm * 128 + qr * 4;
  const int ccol = bcol + wn * 64 + fr;
#pragma unroll
  for (int n = 0; n < 4; ++n) {
    const int col = ccol + n * 16;
    const float badd = (EPI == 0) ? bias[col] : 0.f;
#pragma unroll
    for (int m = 0; m < 8; ++m) {
      const int row = crow + m * 16;
#pragma unroll
      for (int j = 0; j < 4; ++j) {
        const float vv = acc[m][n][j];
        if (EPI == 0)
          outb[(size_t)(row + j) * LDC + col] = (bf16_t)(vv + badd);
        else if (EPI == 1)
          outb[(size_t)(row + j) * LDC + col] = (bf16_t)(vv * 0.03125f);
        else
          outb[(size_t)(row + j) * LDC + col] = (bf16_t)vv;
      }
    }
  }
#undef SA
#undef SB
}

// ---------------------------------------------------------------------------
__global__ __launch_bounds__(256) void cast_f32_bf16(
    const float* __restrict__ in, bf16_t* __restrict__ out, long n4) {
  const long stride = (long)gridDim.x * blockDim.x;
  for (long i = (long)blockIdx.x * blockDim.x + threadIdx.x; i < n4;
       i += stride) {
    f32x4 x = *(const f32x4*)(in + i * 4);
    bf16x4 o;
#pragma unroll
    for (int j = 0; j < 4; ++j) o[j] = (bf16_t)x[j];
    *(bf16x4*)(out + i * 4) = o;
  }
}

// v [z][SEQ][HID] -> vT [z][HID][SEQ]
__global__ __launch_bounds__(256) void transpose_bf16_k(
    const bf16_t* __restrict__ in, bf16_t* __restrict__ out) {
  __shared__ bf16_t tile[64][72];
  const int z = blockIdx.z;
  const bf16_t* src = in + (size_t)z * SEQ * HID;
  bf16_t* dst = out + (size_t)z * SEQ * HID;
  const int r0 = blockIdx.x * 64;
  const int c0 = blockIdx.y * 64;
  const int t = threadIdx.x;
  const int tx = t & 7;
  const int ty = t >> 3;
#pragma unroll
  for (int i = 0; i < 2; ++i) {
    const int r = ty + i * 32;
    bf16x8 vv = *(const bf16x8*)(src + (size_t)(r0 + r) * HID + c0 + tx * 8);
    *(bf16x8*)&tile[r][tx * 8] = vv;
  }
  __syncthreads();
#pragma unroll
  for (int i = 0; i < 2; ++i) {
    const int c = ty + i * 32;
    bf16x8 ov;
#pragma unroll
    for (int j = 0; j < 8; ++j) ov[j] = tile[tx * 8 + j][c];
    *(bf16x8*)(dst + (size_t)(c0 + c) * SEQ + r0 + tx * 8) = ov;
  }
}

// in-place masked softmax over rows of [B*S, S] bf16
__global__ __launch_bounds__(256) void softmax_rows(
    bf16_t* __restrict__ sc, const int* __restrict__ mask) {
  const int row = blockIdx.x;
  const int b = row >> 11;
  bf16_t* p = sc + (size_t)row * SEQ;
  const int* mrow = mask + (size_t)b * SEQ;
  const int t = threadIdx.x;
  const int wave = t >> 6;
  const int lane = t & 63;

  bf16x8 v = *(const bf16x8*)(p + t * 8);
  const int4 m0 = *(const int4*)(mrow + t * 8);
  const int4 m1 = *(const int4*)(mrow + t * 8 + 4);
  const int mk[8] = {m0.x, m0.y, m0.z, m0.w, m1.x, m1.y, m1.z, m1.w};

  float vals[8];
  float mx = -3.4e38f;
#pragma unroll
  for (int j = 0; j < 8; ++j) {
    float s = (float)v[j];
    if (mk[j] == 0) s = MASK_NEG;
    vals[j] = s;
    mx = fmaxf(mx, s);
  }
#pragma unroll
  for (int off = 32; off > 0; off >>= 1)
    mx = fmaxf(mx, __shfl_xor(mx, off, 64));
  __shared__ float red[4];
  if (lane == 0) red[wave] = mx;
  __syncthreads();
  mx = fmaxf(fmaxf(red[0], red[1]), fmaxf(red[2], red[3]));
  __syncthreads();

  float sum = 0.f;
#pragma unroll
  for (int j = 0; j < 8; ++j) {
    vals[j] = __expf(vals[j] - mx);
    sum += vals[j];
  }
#pragma unroll
  for (int off = 32; off > 0; off >>= 1) sum += __shfl_xor(sum, off, 64);
  if (lane == 0) red[wave] = sum;
  __syncthreads();
  sum = red[0] + red[1] + red[2] + red[3];
  const float inv = 1.f / sum;
  bf16x8 o;
#pragma unroll
  for (int j = 0; j < 8; ++j) o[j] = (bf16_t)(vals[j] * inv);
  *(bf16x8*)(p + t * 8) = o;
}

// y = x + attn0 + attn1 (bf16 split-K partials); LayerNorm(y) -> xout (+bf16)
__global__ __launch_bounds__(256) void resid_ln(
    const bf16_t* __restrict__ part0, const bf16_t* __restrict__ part1,
    const float* __restrict__ xin, const float* __restrict__ lnw,
    const float* __restrict__ lnb, float* __restrict__ xout,
    bf16_t* __restrict__ xbout) {
  const int row = blockIdx.x;
  const int t = threadIdx.x;
  const int wave = t >> 6;
  const int lane = t & 63;
  const size_t base = (size_t)row * HID + t * 4;
  const bf16x4 a0 = *(const bf16x4*)(part0 + base);
  const bf16x4 a1 = *(const bf16x4*)(part1 + base);
  const f32x4 xv = *(const f32x4*)(xin + base);
  f32x4 y;
#pragma unroll
  for (int j = 0; j < 4; ++j) y[j] = (float)a0[j] + (float)a1[j] + xv[j];
  float s1 = y[0] + y[1] + y[2] + y[3];
  float s2 = y[0] * y[0] + y[1] * y[1] + y[2] * y[2] + y[3] * y[3];
#pragma unroll
  for (int off = 32; off > 0; off >>= 1) {
    s1 += __shfl_xor(s1, off, 64);
    s2 += __shfl_xor(s2, off, 64);
  }
  __shared__ float red[8];
  if (lane == 0) {
    red[wave] = s1;
    red[4 + wave] = s2;
  }
  __syncthreads();
  s1 = red[0] + red[1] + red[2] + red[3];
  s2 = red[4] + red[5] + red[6] + red[7];
  const float mu = s1 * (1.f / HID);
  const float var = s2 * (1.f / HID) - mu * mu;
  const float rs = rsqrtf(var + LN_EPS);
  const f32x4 wv = *(const f32x4*)(lnw + t * 4);
  const f32x4 bv = *(const f32x4*)(lnb + t * 4);
  f32x4 o;
#pragma unroll
  for (int j = 0; j < 4; ++j) o[j] = wv[j] * ((y[j] - mu) * rs) + bv[j];
  *(f32x4*)(xout + base) = o;
  if (xbout != nullptr) {
    bf16x4 ob;
#pragma unroll
    for (int j = 0; j < 4; ++j) ob[j] = (bf16_t)o[j];
    *(bf16x4*)(xbout + base) = ob;
  }
}

// ---------------------------------------------------------------------------
extern "C" void kernel_launch(void* const* d_in, const int* in_sizes, int n_in,
                              void* d_out, int out_size, void* d_ws,
                              size_t ws_size, hipStream_t stream) {
  const float* x_in = (const float*)d_in[0];
  const int* mask = (const int*)d_in[1];
  const float* Wq = (const float*)d_in[2];
  const float* bq = (const float*)d_in[3];
  const float* Wk = (const float*)d_in[4];
  const float* bk = (const float*)d_in[5];
  const float* Wv = (const float*)d_in[6];
  const float* bv = (const float*)d_in[7];
  const float* lnw = (const float*)d_in[8];
  const float* lnb = (const float*)d_in[9];
  float* out = (float*)d_out;

  char* ws = (char*)d_ws;
  size_t off = 0;
  auto alloc = [&](size_t bytes) {
    char* p = ws + off;
    off += (bytes + 255) & ~(size_t)255;
    return (void*)p;
  };
  const size_t LHH = (size_t)NL * HID * HID;
  bf16_t* wqb = (bf16_t*)alloc(LHH * 2);
  bf16_t* wkb = (bf16_t*)alloc(LHH * 2);
  bf16_t* wvb = (bf16_t*)alloc(LHH * 2);
  bf16_t* xb = (bf16_t*)alloc((size_t)MR * HID * 2);
  bf16_t* q = (bf16_t*)alloc((size_t)MR * HID * 2);
  bf16_t* k = (bf16_t*)alloc((size_t)MR * HID * 2);
  bf16_t* v = (bf16_t*)alloc((size_t)MR * HID * 2);
  bf16_t* vT = (bf16_t*)alloc((size_t)MR * HID * 2);
  bf16_t* scores = (bf16_t*)alloc((size_t)BB * SEQ * SEQ * 2);
  bf16_t* attn0 = (bf16_t*)alloc((size_t)MR * HID * 2);
  bf16_t* attn1 = (bf16_t*)alloc((size_t)MR * HID * 2);
  float* xbuf = (float*)alloc((size_t)MR * HID * 4);
  if (off > ws_size) return;

  cast_f32_bf16<<<2048, 256, 0, stream>>>(Wq, wqb, (long)(LHH / 4));
  cast_f32_bf16<<<2048, 256, 0, stream>>>(Wk, wkb, (long)(LHH / 4));
  cast_f32_bf16<<<2048, 256, 0, stream>>>(Wv, wvb, (long)(LHH / 4));
  cast_f32_bf16<<<2048, 256, 0, stream>>>(x_in, xb, (long)((size_t)MR * HID / 4));

  for (int l = 0; l < NL; ++l) {
    const size_t wo = (size_t)l * HID * HID;
    // QKV projections: grid 3*32*4 = 384
    gemm8<0><<<384, 512, 0, stream>>>(xb, wqb + wo, wkb + wo, wvb + wo,
                                      bq + (size_t)l * HID, bk + (size_t)l * HID,
                                      bv + (size_t)l * HID, q, k, v);
    // V^T for the PV GEMM
    transpose_bf16_k<<<dim3(SEQ / 64, HID / 64, BB), 256, 0, stream>>>(v, vT);
    // scores = q k^T / sqrt(H): grid 4*8*8 = 256
    gemm8<1><<<256, 512, 0, stream>>>(q, k, nullptr, nullptr, nullptr, nullptr,
                                      nullptr, scores, nullptr, nullptr);
    // masked softmax (in place)
    softmax_rows<<<MR, 256, 0, stream>>>(scores, mask);
    // attn partials = probs @ v (split-K 2): grid 8*8*4 = 256
    gemm8<2><<<256, 512, 0, stream>>>(scores, vT, nullptr, nullptr, nullptr,
                                      nullptr, nullptr, attn0, attn1, nullptr);
    // residual + LayerNorm (+ bf16 recast for next layer)
    const float* xi = (l == 0) ? x_in : xbuf;
    float* xo = (l == NL - 1) ? out : xbuf;
    bf16_t* xbo = (l == NL - 1) ? nullptr : xb;
    resid_ln<<<MR, 256, 0, stream>>>(attn0, attn1, xi, lnw + (size_t)l * HID,
                                     lnb + (size_t)l * HID, xo, xbo);
  }
}

// Round 5
// 716.210 us; speedup vs baseline: 1.0221x; 1.0221x over previous
//
#include <hip/hip_runtime.h>
#include <stdint.h>

typedef __bf16 bf16_t;
typedef __bf16 bf16x8 __attribute__((ext_vector_type(8)));
typedef __bf16 bf16x4 __attribute__((ext_vector_type(4)));
typedef float f32x4 __attribute__((ext_vector_type(4)));
typedef unsigned int u32;

#define DEVINL static __device__ __forceinline__

constexpr int BB = 4;
constexpr int SEQ = 2048;
constexpr int HID = 1024;
constexpr int NL = 4;
constexpr int MR = BB * SEQ;  // 8192
constexpr float LN_EPS = 1e-5f;
constexpr float MASK_NEG = -1e9f;

DEVINL f32x4 mfma16x16x32(bf16x8 a, bf16x8 b, f32x4 c) {
  return __builtin_amdgcn_mfma_f32_16x16x32_bf16(a, b, c, 0, 0, 0);
}

// async global->LDS, 16B/lane; LDS dest wave-uniform base + lane*16.
DEVINL void gload_lds16(const bf16_t* g, bf16_t* l) {
  __builtin_amdgcn_global_load_lds(
      (const __attribute__((address_space(1))) u32*)g,
      (__attribute__((address_space(3))) u32*)l, 16, 0, 0);
}

// ---------------------------------------------------------------------------
// NT GEMM, 512 threads (8 waves), XOR slot-swizzled LDS, counted-vmcnt
// staging, setprio around MFMA clusters.
//
// EPI 0 (QKV): BM=256 BN=128, waves 4Mx2N, per-wave 64x64 (acc 4x4).
//   Grid = 32*8*3 = 768 = 3.0 exact rounds of 256 CUs (fixes the 1.5-round
//   quantization of the 256^2 version). 2 phases per K-tile, 16 MFMA each.
//   Staging: p0 -> A(kt+1) all 4 chunks; p1 -> B(kt+2) both chunks.
//   Gate (end of p1): vmcnt(2). Drain-set proof: after the kt-1 gate only
//   B(kt+1)[2] is outstanding; kt adds A(kt+1)[4] + B(kt+2)[2]; vmcnt(2)
//   retires the 6 oldest = B(kt+1)+A(kt+1) = exactly what kt+1 reads.
//   Race-freedom: A(kt+1) overwrites A(kt-1), fully read by kt-1's last
//   barrier; B(kt+2) overwrites B(kt), fully read in kt's p0 (B-frags are
//   all consumed before p0's post-MFMA barrier; SB issues in p1).
// EPI 1 (QK^T) / EPI 2 (PV split-K2): unchanged round-4 256^2 4-phase path
//   (control group for this round's experiment).
// ---------------------------------------------------------------------------
template <int EPI>
__global__ __launch_bounds__(512, 2) void gemm8(
    const bf16_t* __restrict__ Ab, const bf16_t* __restrict__ B0,
    const bf16_t* __restrict__ B1, const bf16_t* __restrict__ B2,
    const float* __restrict__ bias0, const float* __restrict__ bias1,
    const float* __restrict__ bias2, bf16_t* __restrict__ o0,
    bf16_t* __restrict__ o1, bf16_t* __restrict__ o2) {
  constexpr int BM = 256;
  constexpr int BN = (EPI == 0) ? 128 : 256;
  constexpr int WN = (EPI == 0) ? 2 : 4;   // waves along N
  constexpr int WM = 8 / WN;               // waves along M
  constexpr int MREP = BM / (WM * 16);     // EPI0: 4, else 8
  constexpr int NREP = BN / (WN * 16);     // 4
  constexpr int CA = BM / 64;              // 4
  constexpr int CB = BN / 64;              // EPI0: 2, else 4
  constexpr int TMn = (EPI == 0) ? 32 : 8;
  constexpr int TNn = (EPI == 0) ? 8 : ((EPI == 1) ? 8 : 4);
  constexpr int LDA = (EPI == 2) ? SEQ : HID;
  constexpr int LDB = (EPI == 2) ? SEQ : HID;
  constexpr int LDC = (EPI == 1) ? SEQ : HID;
  constexpr int NT = 16;  // K extent 1024 everywhere (PV split-K halves 2048)

  __shared__ bf16_t lA[2 * BM * 64];
  __shared__ bf16_t lB[2 * BN * 64];

  // bijective XCD swizzle (all grids % 8 == 0)
  const int nwg = gridDim.x;
  int Lb = blockIdx.x;
  Lb = (Lb & 7) * (nwg >> 3) + (Lb >> 3);
  const int z = Lb / (TMn * TNn);
  const int rem = Lb - z * (TMn * TNn);
  const int tm = rem / TNn;
  const int tn = rem - tm * TNn;
  const int brow = tm * BM, bcol = tn * BN;

  const bf16_t* A;
  const bf16_t* B;
  const float* bias = nullptr;
  bf16_t* outb = nullptr;
  if (EPI == 0) {
    A = Ab;
    B = (z == 0) ? B0 : (z == 1) ? B1 : B2;
    bias = (z == 0) ? bias0 : (z == 1) ? bias1 : bias2;
    outb = (z == 0) ? o0 : (z == 1) ? o1 : o2;
  } else if (EPI == 1) {
    A = Ab + (size_t)z * SEQ * HID;
    B = B0 + (size_t)z * SEQ * HID;
    outb = o0 + (size_t)z * SEQ * SEQ;
  } else {
    const int zb = z >> 1, kh = z & 1;
    A = Ab + (size_t)zb * SEQ * SEQ + kh * 1024;  // scores K-half
    B = B0 + (size_t)zb * HID * SEQ + kh * 1024;  // vT K-half
    outb = ((kh == 0) ? o0 : o1) + (size_t)zb * SEQ * HID;
  }

  const int t = threadIdx.x, wave = t >> 6, lane = t & 63;
  const int wm = wave / WN, wn = wave % WN;
  const int fr = lane & 15, kb = lane >> 4;
  const int srow = t >> 3;               // 0..63 (64 rows per gload call)
  const int cbk = (t & 7) ^ (srow & 7);  // pre-swizzled source slot
  const bf16_t* pAs = A + (size_t)(brow + srow) * LDA + cbk * 8;
  const bf16_t* pBs = B + (size_t)(bcol + srow) * LDB + cbk * 8;
  bf16_t* lAw = lA + wave * 512;
  bf16_t* lBw = lB + wave * 512;

  // stage 64-row chunk h of K-tile X into parity X&1
#define SA(X_, h_)                                                  \
  gload_lds16(pAs + (size_t)((h_)*64) * LDA + (X_)*64,              \
              lAw + ((X_)&1) * (BM * 64) + (h_)*4096)
#define SB(X_, h_)                                                  \
  gload_lds16(pBs + (size_t)((h_)*64) * LDB + (X_)*64,              \
              lBw + ((X_)&1) * (BN * 64) + (h_)*4096)

  const char* lAc = (const char*)lA;
  const char* lBc = (const char*)lB;
  const int cX0 = ((kb ^ (fr & 7)) << 4);  // swizzled ds_read col (ks=0)
  const int cX1 = cX0 ^ 64;                // ks=1

  f32x4 acc[MREP][NREP] = {};

  if constexpr (EPI == 0) {
    // ------------------ 2-phase schedule (new this round) ------------------
    SA(0, 0); SA(0, 1); SA(0, 2); SA(0, 3);
    SB(0, 0); SB(0, 1);
    SB(1, 0); SB(1, 1);
    asm volatile("s_waitcnt vmcnt(2)" ::: "memory");  // A0,B0 landed
    __builtin_amdgcn_s_barrier();

    for (int kt = 0; kt < NT; ++kt) {
      const char* aB = lAc + (kt & 1) * (BM * 128) + wm * (MREP * 16 * 128);
      const char* bB = lBc + (kt & 1) * (BN * 128) + wn * (NREP * 16 * 128);
      // p0: all B-frags + A m=0..1, stage A(kt+1)
      bf16x8 bf_[NREP][2];
#pragma unroll
      for (int n = 0; n < NREP; ++n) {
        const int rb = (n * 16 + fr) * 128;
        bf_[n][0] = *(const bf16x8*)(bB + rb + cX0);
        bf_[n][1] = *(const bf16x8*)(bB + rb + cX1);
      }
      bf16x8 a0[2][2];
#pragma unroll
      for (int m = 0; m < 2; ++m) {
        const int ra = (m * 16 + fr) * 128;
        a0[m][0] = *(const bf16x8*)(aB + ra + cX0);
        a0[m][1] = *(const bf16x8*)(aB + ra + cX1);
      }
      if (kt + 1 < NT) { SA(kt + 1, 0); SA(kt + 1, 1); SA(kt + 1, 2); SA(kt + 1, 3); }
      __builtin_amdgcn_s_barrier();
      __builtin_amdgcn_s_setprio(1);
#pragma unroll
      for (int m = 0; m < 2; ++m)
#pragma unroll
        for (int n = 0; n < NREP; ++n) {
          acc[m][n] = mfma16x16x32(a0[m][0], bf_[n][0], acc[m][n]);
          acc[m][n] = mfma16x16x32(a0[m][1], bf_[n][1], acc[m][n]);
        }
      __builtin_amdgcn_s_setprio(0);
      __builtin_amdgcn_s_barrier();
      // p1: A m=2..3, stage B(kt+2), gate
      bf16x8 a1[2][2];
#pragma unroll
      for (int m = 0; m < 2; ++m) {
        const int ra = ((m + 2) * 16 + fr) * 128;
        a1[m][0] = *(const bf16x8*)(aB + ra + cX0);
        a1[m][1] = *(const bf16x8*)(aB + ra + cX1);
      }
      if (kt + 2 < NT) { SB(kt + 2, 0); SB(kt + 2, 1); }
      __builtin_amdgcn_s_barrier();
      __builtin_amdgcn_s_setprio(1);
#pragma unroll
      for (int m = 0; m < 2; ++m)
#pragma unroll
        for (int n = 0; n < NREP; ++n) {
          acc[m + 2][n] = mfma16x16x32(a1[m][0], bf_[n][0], acc[m + 2][n]);
          acc[m + 2][n] = mfma16x16x32(a1[m][1], bf_[n][1], acc[m + 2][n]);
        }
      __builtin_amdgcn_s_setprio(0);
      if (kt < NT - 2)
        asm volatile("s_waitcnt vmcnt(2)" ::: "memory");
      else
        asm volatile("s_waitcnt vmcnt(0)" ::: "memory");
      __builtin_amdgcn_s_barrier();
    }
  } else {
    // ------------------ round-4 4-phase schedule (control) -----------------
    SA(0, 0); SA(0, 1); SA(0, 2); SA(0, 3);
    SB(0, 0); SB(0, 1); SB(0, 2); SB(0, 3);
    SA(1, 0); SA(1, 2);
    SB(1, 0); SB(1, 1); SB(1, 2); SB(1, 3);
    asm volatile("s_waitcnt vmcnt(6)" ::: "memory");
    __builtin_amdgcn_s_barrier();

    for (int kt = 0; kt < NT; ++kt) {
      const char* aB = lAc + (kt & 1) * (BM * 128) + wm * (MREP * 16 * 128);
      const char* bB = lBc + (kt & 1) * (BN * 128) + wn * (NREP * 16 * 128);
      bf16x8 bf_[NREP][2];
#pragma unroll
      for (int p = 0; p < 4; ++p) {
        if (p == 0) {
#pragma unroll
          for (int n = 0; n < NREP; ++n) {
            const int rb = (n * 16 + fr) * 128;
            bf_[n][0] = *(const bf16x8*)(bB + rb + cX0);
            bf_[n][1] = *(const bf16x8*)(bB + rb + cX1);
          }
        }
        const int ra0 = (p * 32 + fr) * 128;
        const int ra1 = (p * 32 + 16 + fr) * 128;
        bf16x8 a00 = *(const bf16x8*)(aB + ra0 + cX0);
        bf16x8 a01 = *(const bf16x8*)(aB + ra0 + cX1);
        bf16x8 a10 = *(const bf16x8*)(aB + ra1 + cX0);
        bf16x8 a11 = *(const bf16x8*)(aB + ra1 + cX1);
        if (p == 0 && kt + 1 < NT) { SA(kt + 1, 1); SA(kt + 1, 3); }
        if (p == 1 && kt + 2 < NT) { SB(kt + 2, 0); SB(kt + 2, 1); }
        if (p == 2 && kt + 2 < NT) { SA(kt + 2, 0); SA(kt + 2, 2); }
        if (p == 3 && kt + 2 < NT) { SB(kt + 2, 2); SB(kt + 2, 3); }
        __builtin_amdgcn_s_barrier();
        __builtin_amdgcn_s_setprio(1);
#pragma unroll
        for (int n = 0; n < NREP; ++n) {
          acc[2 * p][n] = mfma16x16x32(a00, bf_[n][0], acc[2 * p][n]);
          acc[2 * p][n] = mfma16x16x32(a01, bf_[n][1], acc[2 * p][n]);
          acc[2 * p + 1][n] = mfma16x16x32(a10, bf_[n][0], acc[2 * p + 1][n]);
          acc[2 * p + 1][n] = mfma16x16x32(a11, bf_[n][1], acc[2 * p + 1][n]);
        }
        __builtin_amdgcn_s_setprio(0);
        if (p == 3) {
          if (kt < NT - 3)
            asm volatile("s_waitcnt vmcnt(6)" ::: "memory");
          else
            asm volatile("s_waitcnt vmcnt(0)" ::: "memory");
        }
        __builtin_amdgcn_s_barrier();
      }
    }
  }

  // C/D layout (m89): col = lane&15, row = (lane>>4)*4 + j
  const int qr = lane >> 4;
  const int crow = brow + wm * (MREP * 16) + qr * 4;
  const int ccol = bcol + wn * (NREP * 16) + fr;
#pragma unroll
  for (int n = 0; n < NREP; ++n) {
    const int col = ccol + n * 16;
    const float badd = (EPI == 0) ? bias[col] : 0.f;
#pragma unroll
    for (int m = 0; m < MREP; ++m) {
      const int row = crow + m * 16;
#pragma unroll
      for (int j = 0; j < 4; ++j) {
        const float vv = acc[m][n][j];
        if (EPI == 0)
          outb[(size_t)(row + j) * LDC + col] = (bf16_t)(vv + badd);
        else if (EPI == 1)
          outb[(size_t)(row + j) * LDC + col] = (bf16_t)(vv * 0.03125f);
        else
          outb[(size_t)(row + j) * LDC + col] = (bf16_t)vv;
      }
    }
  }
#undef SA
#undef SB
}

// ---------------------------------------------------------------------------
__global__ __launch_bounds__(256) void cast_f32_bf16(
    const float* __restrict__ in, bf16_t* __restrict__ out, long n4) {
  const long stride = (long)gridDim.x * blockDim.x;
  for (long i = (long)blockIdx.x * blockDim.x + threadIdx.x; i < n4;
       i += stride) {
    f32x4 x = *(const f32x4*)(in + i * 4);
    bf16x4 o;
#pragma unroll
    for (int j = 0; j < 4; ++j) o[j] = (bf16_t)x[j];
    *(bf16x4*)(out + i * 4) = o;
  }
}

// v [z][SEQ][HID] -> vT [z][HID][SEQ]
__global__ __launch_bounds__(256) void transpose_bf16_k(
    const bf16_t* __restrict__ in, bf16_t* __restrict__ out) {
  __shared__ bf16_t tile[64][72];
  const int z = blockIdx.z;
  const bf16_t* src = in + (size_t)z * SEQ * HID;
  bf16_t* dst = out + (size_t)z * SEQ * HID;
  const int r0 = blockIdx.x * 64;
  const int c0 = blockIdx.y * 64;
  const int t = threadIdx.x;
  const int tx = t & 7;
  const int ty = t >> 3;
#pragma unroll
  for (int i = 0; i < 2; ++i) {
    const int r = ty + i * 32;
    bf16x8 vv = *(const bf16x8*)(src + (size_t)(r0 + r) * HID + c0 + tx * 8);
    *(bf16x8*)&tile[r][tx * 8] = vv;
  }
  __syncthreads();
#pragma unroll
  for (int i = 0; i < 2; ++i) {
    const int c = ty + i * 32;
    bf16x8 ov;
#pragma unroll
    for (int j = 0; j < 8; ++j) ov[j] = tile[tx * 8 + j][c];
    *(bf16x8*)(dst + (size_t)(c0 + c) * SEQ + r0 + tx * 8) = ov;
  }
}

// in-place masked softmax over rows of [B*S, S] bf16
__global__ __launch_bounds__(256) void softmax_rows(
    bf16_t* __restrict__ sc, const int* __restrict__ mask) {
  const int row = blockIdx.x;
  const int b = row >> 11;
  bf16_t* p = sc + (size_t)row * SEQ;
  const int* mrow = mask + (size_t)b * SEQ;
  const int t = threadIdx.x;
  const int wave = t >> 6;
  const int lane = t & 63;

  bf16x8 v = *(const bf16x8*)(p + t * 8);
  const int4 m0 = *(const int4*)(mrow + t * 8);
  const int4 m1 = *(const int4*)(mrow + t * 8 + 4);
  const int mk[8] = {m0.x, m0.y, m0.z, m0.w, m1.x, m1.y, m1.z, m1.w};

  float vals[8];
  float mx = -3.4e38f;
#pragma unroll
  for (int j = 0; j < 8; ++j) {
    float s = (float)v[j];
    if (mk[j] == 0) s = MASK_NEG;
    vals[j] = s;
    mx = fmaxf(mx, s);
  }
#pragma unroll
  for (int off = 32; off > 0; off >>= 1)
    mx = fmaxf(mx, __shfl_xor(mx, off, 64));
  __shared__ float red[4];
  if (lane == 0) red[wave] = mx;
  __syncthreads();
  mx = fmaxf(fmaxf(red[0], red[1]), fmaxf(red[2], red[3]));
  __syncthreads();

  float sum = 0.f;
#pragma unroll
  for (int j = 0; j < 8; ++j) {
    vals[j] = __expf(vals[j] - mx);
    sum += vals[j];
  }
#pragma unroll
  for (int off = 32; off > 0; off >>= 1) sum += __shfl_xor(sum, off, 64);
  if (lane == 0) red[wave] = sum;
  __syncthreads();
  sum = red[0] + red[1] + red[2] + red[3];
  const float inv = 1.f / sum;
  bf16x8 o;
#pragma unroll
  for (int j = 0; j < 8; ++j) o[j] = (bf16_t)(vals[j] * inv);
  *(bf16x8*)(p + t * 8) = o;
}

// y = x + attn0 + attn1 (bf16 split-K partials); LayerNorm(y) -> xout (+bf16)
__global__ __launch_bounds__(256) void resid_ln(
    const bf16_t* __restrict__ part0, const bf16_t* __restrict__ part1,
    const float* __restrict__ xin, const float* __restrict__ lnw,
    const float* __restrict__ lnb, float* __restrict__ xout,
    bf16_t* __restrict__ xbout) {
  const int row = blockIdx.x;
  const int t = threadIdx.x;
  const int wave = t >> 6;
  const int lane = t & 63;
  const size_t base = (size_t)row * HID + t * 4;
  const bf16x4 a0 = *(const bf16x4*)(part0 + base);
  const bf16x4 a1 = *(const bf16x4*)(part1 + base);
  const f32x4 xv = *(const f32x4*)(xin + base);
  f32x4 y;
#pragma unroll
  for (int j = 0; j < 4; ++j) y[j] = (float)a0[j] + (float)a1[j] + xv[j];
  float s1 = y[0] + y[1] + y[2] + y[3];
  float s2 = y[0] * y[0] + y[1] * y[1] + y[2] * y[2] + y[3] * y[3];
#pragma unroll
  for (int off = 32; off > 0; off >>= 1) {
    s1 += __shfl_xor(s1, off, 64);
    s2 += __shfl_xor(s2, off, 64);
  }
  __shared__ float red[8];
  if (lane == 0) {
    red[wave] = s1;
    red[4 + wave] = s2;
  }
  __syncthreads();
  s1 = red[0] + red[1] + red[2] + red[3];
  s2 = red[4] + red[5] + red[6] + red[7];
  const float mu = s1 * (1.f / HID);
  const float var = s2 * (1.f / HID) - mu * mu;
  const float rs = rsqrtf(var + LN_EPS);
  const f32x4 wv = *(const f32x4*)(lnw + t * 4);
  const f32x4 bv = *(const f32x4*)(lnb + t * 4);
  f32x4 o;
#pragma unroll
  for (int j = 0; j < 4; ++j) o[j] = wv[j] * ((y[j] - mu) * rs) + bv[j];
  *(f32x4*)(xout + base) = o;
  if (xbout != nullptr) {
    bf16x4 ob;
#pragma unroll
    for (int j = 0; j < 4; ++j) ob[j] = (bf16_t)o[j];
    *(bf16x4*)(xbout + base) = ob;
  }
}

// ---------------------------------------------------------------------------
extern "C" void kernel_launch(void* const* d_in, const int* in_sizes, int n_in,
                              void* d_out, int out_size, void* d_ws,
                              size_t ws_size, hipStream_t stream) {
  const float* x_in = (const float*)d_in[0];
  const int* mask = (const int*)d_in[1];
  const float* Wq = (const float*)d_in[2];
  const float* bq = (const float*)d_in[3];
  const float* Wk = (const float*)d_in[4];
  const float* bk = (const float*)d_in[5];
  const float* Wv = (const float*)d_in[6];
  const float* bv = (const float*)d_in[7];
  const float* lnw = (const float*)d_in[8];
  const float* lnb = (const float*)d_in[9];
  float* out = (float*)d_out;

  char* ws = (char*)d_ws;
  size_t off = 0;
  auto alloc = [&](size_t bytes) {
    char* p = ws + off;
    off += (bytes + 255) & ~(size_t)255;
    return (void*)p;
  };
  const size_t LHH = (size_t)NL * HID * HID;
  bf16_t* wqb = (bf16_t*)alloc(LHH * 2);
  bf16_t* wkb = (bf16_t*)alloc(LHH * 2);
  bf16_t* wvb = (bf16_t*)alloc(LHH * 2);
  bf16_t* xb = (bf16_t*)alloc((size_t)MR * HID * 2);
  bf16_t* q = (bf16_t*)alloc((size_t)MR * HID * 2);
  bf16_t* k = (bf16_t*)alloc((size_t)MR * HID * 2);
  bf16_t* v = (bf16_t*)alloc((size_t)MR * HID * 2);
  bf16_t* vT = (bf16_t*)alloc((size_t)MR * HID * 2);
  bf16_t* scores = (bf16_t*)alloc((size_t)BB * SEQ * SEQ * 2);
  bf16_t* attn0 = (bf16_t*)alloc((size_t)MR * HID * 2);
  bf16_t* attn1 = (bf16_t*)alloc((size_t)MR * HID * 2);
  float* xbuf = (float*)alloc((size_t)MR * HID * 4);
  if (off > ws_size) return;

  cast_f32_bf16<<<2048, 256, 0, stream>>>(Wq, wqb, (long)(LHH / 4));
  cast_f32_bf16<<<2048, 256, 0, stream>>>(Wk, wkb, (long)(LHH / 4));
  cast_f32_bf16<<<2048, 256, 0, stream>>>(Wv, wvb, (long)(LHH / 4));
  cast_f32_bf16<<<2048, 256, 0, stream>>>(x_in, xb, (long)((size_t)MR * HID / 4));

  for (int l = 0; l < NL; ++l) {
    const size_t wo = (size_t)l * HID * HID;
    // QKV projections: grid 3 * 32 * 8 = 768 (3 exact CU rounds)
    gemm8<0><<<768, 512, 0, stream>>>(xb, wqb + wo, wkb + wo, wvb + wo,
                                      bq + (size_t)l * HID, bk + (size_t)l * HID,
                                      bv + (size_t)l * HID, q, k, v);
    // V^T for the PV GEMM
    transpose_bf16_k<<<dim3(SEQ / 64, HID / 64, BB), 256, 0, stream>>>(v, vT);
    // scores = q k^T / sqrt(H): grid 4*8*8 = 256
    gemm8<1><<<256, 512, 0, stream>>>(q, k, nullptr, nullptr, nullptr, nullptr,
                                      nullptr, scores, nullptr, nullptr);
    // masked softmax (in place)
    softmax_rows<<<MR, 256, 0, stream>>>(scores, mask);
    // attn partials = probs @ v (split-K 2): grid 8*8*4 = 256
    gemm8<2><<<256, 512, 0, stream>>>(scores, vT, nullptr, nullptr, nullptr,
                                      nullptr, nullptr, attn0, attn1, nullptr);
    // residual + LayerNorm (+ bf16 recast for next layer)
    const float* xi = (l == 0) ? x_in : xbuf;
    float* xo = (l == NL - 1) ? out : xbuf;
    bf16_t* xbo = (l == NL - 1) ? nullptr : xb;
    resid_ln<<<MR, 256, 0, stream>>>(attn0, attn1, xi, lnw + (size_t)l * HID,
                                     lnb + (size_t)l * HID, xo, xbo);
  }
}